// Round 5
// baseline (76.537 us; speedup 1.0000x reference)
//
#include <hip/hip_runtime.h>
#include <math.h>
#include <stdint.h>

// Chamfer loss, B=16, N=M=4096, D=3, fp32 in/out — MFMA formulation, R14.
//
// d^2(p,t) = |p|^2 + (|t|^2 - 2 p.t); the bracket via v_mfma_f32_32x32x16_f16:
//   A row (candidate): [tx, ty, tz, h1, h2, 0,0,0]   (k=0..7; hi-lane k=8..15 garbage)
//   B col (query):     [-2px,-2py,-2pz, 1, 1, 0,0,0] (k=0..7; k=8..15 ZERO -> annihilates A garbage)
// h1+h2 = two-f16 split of |t|^2 (fp32-accurate). Only error is f16 point
// quantization (~1e-3, passes).
//
// HISTORY: R9=76.0 (1024 blk x 4 waves, dual-chain). R10=94.7 (per-block
// __threadfence = L2 writeback stall, NEVER). R11=83.1 (1024 same-address
// atomics = serialized burst tail, NEVER). R12=79.4 (lb(256,8) 64-VGPR clamp
// broke the chains). R13=76.5 (NULL: per-wave LDS ring, depth-3
// global_load_lds, counted vmcnt — deep per-wave load pipelining does NOT
// help; both VGPR loads and global_load_lds share the TA/L1 path).
//
// R14 theory: R8+R13 double-null means main is not load-ISSUE-bound; the
// surviving mechanism is per-CU memory-level parallelism (MSHR lines): each
// wave-load touches 16 cache lines, ~256 KB/CU streams through a 32 KB L1 at
// ~100% miss, so in-flight BYTES are capped by miss-tracking, not by
// instructions in flight. Only lever: cut per-CU traffic via candidate REUSE.
// R14 doubles queries/block 128->256: 512-thread blocks, 8 waves
// (qhalf=wave&3 -> 4 dual-chain query sets, chalf=wave>>2), grid 512 = exactly
// 2 blocks/CU, 16 waves/CU (same occupancy as R9). Per-CU candidate traffic
// halves (4x66KB -> 2x66KB). Inner loop = R9 verbatim. lb(512,2) = 128-VGPR
// cap, dual-chain (~52 VGPR) untouched — avoids R12's 64-cap trap.
//
// Fixed cost context: harness re-poisons ~256 MB ws each timed iter = ~41.5 us
// of fillBuffer at HBM roofline inside dur_us, + ~10 us graph/launch overhead.
// Untouchable floor ~55 us.

#define BATCH   16
#define NPTS    4096
#define THREADS 512                            // 8 waves/block
#define QPB     256                            // queries per block
#define NITEMS  (2 * BATCH * NPTS)             // 131072
#define MAIN_BLOCKS (2 * BATCH * (NPTS / QPB)) // 512: 256 queries per block

typedef __attribute__((ext_vector_type(8)))  _Float16 half8;
typedef __attribute__((ext_vector_type(16))) float    floatx16;

union Pack16 { float4 f4; _Float16 h[8]; half8 h8; };

__global__ __launch_bounds__(256) void chamfer_prep(
    const float* __restrict__ pred, const float* __restrict__ target,
    float4* __restrict__ packP, float4* __restrict__ packT)
{
    int g = blockIdx.x * 256 + threadIdx.x;       // 0..131071
    int arr = g >> 16;                            // 0=pred, 1=target
    int pt  = g & 65535;                          // b*NPTS + n
    const float* src = arr ? target : pred;
    float x = src[pt * 3 + 0];
    float y = src[pt * 3 + 1];
    float z = src[pt * 3 + 2];
    _Float16 hx = (_Float16)x, hy = (_Float16)y, hz = (_Float16)z;
    float xf = (float)hx, yf = (float)hy, zf = (float)hz;
    float t = xf * xf + yf * yf + zf * zf;        // |q|^2 of the QUANTIZED point
    _Float16 h1 = (_Float16)t;
    _Float16 h2 = (_Float16)(t - (float)h1);
    Pack16 p;
    p.h[0] = hx; p.h[1] = hy; p.h[2] = hz; p.h[3] = h1; p.h[4] = h2;
    p.h[5] = (_Float16)0.0f; p.h[6] = (_Float16)0.0f; p.h[7] = (_Float16)0.0f;
    (arr ? packT : packP)[pt] = p.f4;
}

__device__ inline half8 make_bfrag(const Pack16& praw, bool lo) {
    half8 f;
#pragma unroll
    for (int i = 0; i < 8; ++i) f[i] = (_Float16)0.0f;
    if (lo) {
        f[0] = (_Float16)(praw.h[0] * (_Float16)-2.0f);  // exact x2 scale
        f[1] = (_Float16)(praw.h[1] * (_Float16)-2.0f);
        f[2] = (_Float16)(praw.h[2] * (_Float16)-2.0f);
        f[3] = (_Float16)1.0f;
        f[4] = (_Float16)1.0f;
    }
    return f;
}

__global__ __launch_bounds__(THREADS, 2) void chamfer_main(
    const float4* __restrict__ packP, const float4* __restrict__ packT,
    float* __restrict__ blocksum)
{
    __shared__ float pmin[8][64];   // per-wave mins for its 64 queries
    __shared__ float wsum[4];

    int tid  = threadIdx.x;
    int lane = tid & 63;
    int wave = tid >> 6;            // 0..7
    int qhalf = wave & 3;           // query 64-set (0..3) within the block's 256
    int chalf = wave >> 2;          // candidate half (2048 candidates)
    int l31  = lane & 31;
    bool lo  = lane < 32;

    int id = blockIdx.x;
    int ng = id & 15; id >>= 4;     // query group (256 queries)
    int b  = id & 15; id >>= 4;
    int dir = id;                   // 0: queries=pred, candidates=target

    const float4* qpack = dir ? packT : packP;
    const float4* cpack = dir ? packP : packT;

    // Two B fragments per wave: queries [qbase, qbase+32) and [qbase+32, qbase+64).
    size_t qbase = (size_t)b * NPTS + ng * QPB + qhalf * 64;
    Pack16 prA, prB;
    prA.f4 = qpack[qbase + l31];
    prB.f4 = qpack[qbase + 32 + l31];
    half8 bfragA = make_bfrag(prA, lo);
    half8 bfragB = make_bfrag(prB, lo);

    const float4* cb = cpack + (size_t)b * NPTS + chalf * 2048;

    floatx16 zero, mnA, mnB;
#pragma unroll
    for (int r = 0; r < 16; ++r) { zero[r] = 0.0f; mnA[r] = 1e30f; mnB[r] = 1e30f; }

    // 32 tiles x 64 candidates. Each load-pair feeds TWO independent MFMA/min
    // chains (bfragA vs bfragB) -> MFMA result latency on one chain overlaps
    // VALU issue on the other. NOTE: keep this order — the d0->d2 min pairs
    // fuse to v_min3_f32; two live d-tiles fits easily under the 128-VGPR cap.
#pragma unroll 2
    for (int t = 0; t < 32; ++t) {
        Pack16 a0, a1;
        a0.f4 = cb[t * 64 + l31];
        a1.f4 = cb[t * 64 + 32 + l31];
        floatx16 d0 = __builtin_amdgcn_mfma_f32_32x32x16_f16(a0.h8, bfragA, zero, 0, 0, 0);
        floatx16 d1 = __builtin_amdgcn_mfma_f32_32x32x16_f16(a0.h8, bfragB, zero, 0, 0, 0);
#pragma unroll
        for (int r = 0; r < 16; ++r) mnA[r] = fminf(d0[r], mnA[r]);
#pragma unroll
        for (int r = 0; r < 16; ++r) mnB[r] = fminf(d1[r], mnB[r]);
        floatx16 d2 = __builtin_amdgcn_mfma_f32_32x32x16_f16(a1.h8, bfragA, zero, 0, 0, 0);
        floatx16 d3 = __builtin_amdgcn_mfma_f32_32x32x16_f16(a1.h8, bfragB, zero, 0, 0, 0);
#pragma unroll
        for (int r = 0; r < 16; ++r) mnA[r] = fminf(d2[r], mnA[r]);
#pragma unroll
        for (int r = 0; r < 16; ++r) mnB[r] = fminf(d3[r], mnB[r]);
    }

    // Per-lane 16-reg min trees, fold row-halves across lane^32, publish both
    // query sets (cols l31 / l31+32 of pmin row).
    float mA = fminf(fminf(fminf(mnA[0], mnA[1]),   fminf(mnA[2], mnA[3])),
                     fminf(fminf(mnA[4], mnA[5]),   fminf(mnA[6], mnA[7])));
    mA = fminf(mA, fminf(fminf(fminf(mnA[8], mnA[9]),   fminf(mnA[10], mnA[11])),
                         fminf(fminf(mnA[12], mnA[13]), fminf(mnA[14], mnA[15]))));
    float mB = fminf(fminf(fminf(mnB[0], mnB[1]),   fminf(mnB[2], mnB[3])),
                     fminf(fminf(mnB[4], mnB[5]),   fminf(mnB[6], mnB[7])));
    mB = fminf(mB, fminf(fminf(fminf(mnB[8], mnB[9]),   fminf(mnB[10], mnB[11])),
                         fminf(fminf(mnB[12], mnB[13]), fminf(mnB[14], mnB[15]))));
    mA = fminf(mA, __shfl_xor(mA, 32));
    mB = fminf(mB, __shfl_xor(mB, 32));
    if (lo) {
        pmin[wave][l31]      = mA;
        pmin[wave][l31 + 32] = mB;
    }
    __syncthreads();

    // Waves 0-3: all 64 lanes finish one query each (query = ng*256 + wave*64 + lane):
    // merge candidate halves (wave w vs w+4), add |p|^2, sqrt, full-wave sum.
    if (wave < 4) {
        float mm = fminf(pmin[wave][lane], pmin[wave + 4][lane]);
        Pack16 pr;
        pr.f4 = qpack[(size_t)b * NPTS + ng * QPB + wave * 64 + lane];
        float psq = (float)pr.h[3] + (float)pr.h[4];
        float dist = sqrtf(fmaxf(mm + psq, 0.0f));
#pragma unroll
        for (int off = 1; off <= 32; off <<= 1)
            dist += __shfl_xor(dist, off);
        if (lane == 0) wsum[wave] = dist;
    }
    __syncthreads();

    if (tid == 0)
        blocksum[blockIdx.x] = (wsum[0] + wsum[1]) + (wsum[2] + wsum[3]);
}

__global__ __launch_bounds__(256) void chamfer_finish(
    const float4* __restrict__ bs, float* __restrict__ out)
{
    __shared__ float ws[4];
    int tid = threadIdx.x;
    float s = 0.0f;
    if (tid < 128) {                      // 512 block sums = 128 x float4
        float4 v = bs[tid];
        s = (v.x + v.y) + (v.z + v.w);
    }
#pragma unroll
    for (int off = 1; off <= 32; off <<= 1)
        s += __shfl_xor(s, off);
    int lane = tid & 63, wave = tid >> 6;
    if (lane == 0) ws[wave] = s;
    __syncthreads();
    if (tid == 0) out[0] = (ws[0] + ws[1] + ws[2] + ws[3]) * (1.0f / (float)NITEMS);
}

extern "C" void kernel_launch(void* const* d_in, const int* in_sizes, int n_in,
                              void* d_out, int out_size, void* d_ws, size_t ws_size,
                              hipStream_t stream) {
    const float* pred   = (const float*)d_in[0];
    const float* target = (const float*)d_in[1];
    float* out = (float*)d_out;

    float4* packP = (float4*)d_ws;                              // 1 MB
    float4* packT = packP + (size_t)BATCH * NPTS;               // 1 MB
    float*  blocksum = (float*)(packT + (size_t)BATCH * NPTS);  // 2 KB

    chamfer_prep<<<NITEMS / 256, 256, 0, stream>>>(pred, target, packP, packT);
    chamfer_main<<<MAIN_BLOCKS, THREADS, 0, stream>>>(packP, packT, blocksum);
    chamfer_finish<<<1, 256, 0, stream>>>((const float4*)blocksum, out);
}

// Round 6
// 75.408 us; speedup vs baseline: 1.0150x; 1.0150x over previous
//
#include <hip/hip_runtime.h>
#include <math.h>
#include <stdint.h>

// Chamfer loss, B=16, N=M=4096, D=3, fp32 in/out — MFMA formulation, R15.
//
// d^2(p,t) = |p|^2 + (|t|^2 - 2 p.t); the bracket via v_mfma_f32_32x32x16_f16:
//   A row (candidate): [tx, ty, tz, h1, h2, 0,0,0]   (k=0..7; hi-lane k=8..15 garbage)
//   B col (query):     [-2px,-2py,-2pz, 1, 1, 0,0,0] (k=0..7; k=8..15 ZERO -> annihilates A garbage)
// h1+h2 = two-f16 split of |t|^2 (fp32-accurate). Only error is f16 point
// quantization (~1e-3, passes).
//
// LEDGER: R9=76.0 (baseline). R10=94.7 (per-block fence = L2 writeback, NEVER).
// R11=83.1 (same-address atomic burst ~10us, NEVER). R12=79.4 (64-VGPR clamp).
// R13=76.5 NULL (per-wave LDS ring / deep load pipelining). R14=76.5 NULL
// (halved per-CU footprint). Algebra on R10/R11 (fence≈21.7, atomic≈10.1,
// R10-main measured 42.4) -> R9 main ≈ 20.7us; prep+overhead ≈ 12; fill 41.5.
//
// R15 theory: the INVARIANT across all nulls is chip-wide VMEM volume: 4096
// waves x 32 tiles x 2KB = 268 MB through the TA/L1/L2 return path (~34.5
// TB/s => ~7.8us floor), on top of ~8us VALU issue, poorly overlapped. R13
// pipelined it, R14 shrank the footprint, but NOBODY reduced the volume: in
// R14 each tile is consumed by 4 waves yet loaded 4x from L2. R15 = R14
// verbatim + block-shared LDS staging: per phase (2 x 1024 cands per chalf),
// 8 waves cooperatively global_load_lds bufA (chalf0, waves 0-3) and bufB
// (chalf1, waves 4-7), one sync, 16 tiles of ds_read_b128 + unchanged
// MFMA/min3 body. VMEM volume 268 MB -> 32 MB (8x). LDS 34 KB -> occupancy
// unchanged (2 blk/CU, 16 waves/CU). Accepted cost: 4-way bank conflict on
// 16B-stride ds_read (1.58x on non-critical LDS pipe) — swizzle is next
// round's lever if this lands.
//
// Fixed cost context: harness re-poisons ~256 MB ws each timed iter = ~41.5 us
// of fillBuffer at HBM roofline inside dur_us, + ~10 us graph/launch overhead.
// Untouchable floor ~55 us.

#define BATCH   16
#define NPTS    4096
#define THREADS 512                            // 8 waves/block
#define QPB     256                            // queries per block
#define NITEMS  (2 * BATCH * NPTS)             // 131072
#define MAIN_BLOCKS (2 * BATCH * (NPTS / QPB)) // 512: 256 queries per block

typedef __attribute__((ext_vector_type(8)))  _Float16 half8;
typedef __attribute__((ext_vector_type(16))) float    floatx16;

union Pack16 { float4 f4; _Float16 h[8]; half8 h8; };

// global->LDS DMA: wave-uniform LDS base, per-lane global addr, 16 B/lane.
#define GLL(gsrc, ldst)                                                        \
    __builtin_amdgcn_global_load_lds(                                          \
        (const __attribute__((address_space(1))) void*)(gsrc),                 \
        (__attribute__((address_space(3))) void*)(ldst), 16, 0, 0)

__global__ __launch_bounds__(256) void chamfer_prep(
    const float* __restrict__ pred, const float* __restrict__ target,
    float4* __restrict__ packP, float4* __restrict__ packT)
{
    int g = blockIdx.x * 256 + threadIdx.x;       // 0..131071
    int arr = g >> 16;                            // 0=pred, 1=target
    int pt  = g & 65535;                          // b*NPTS + n
    const float* src = arr ? target : pred;
    float x = src[pt * 3 + 0];
    float y = src[pt * 3 + 1];
    float z = src[pt * 3 + 2];
    _Float16 hx = (_Float16)x, hy = (_Float16)y, hz = (_Float16)z;
    float xf = (float)hx, yf = (float)hy, zf = (float)hz;
    float t = xf * xf + yf * yf + zf * zf;        // |q|^2 of the QUANTIZED point
    _Float16 h1 = (_Float16)t;
    _Float16 h2 = (_Float16)(t - (float)h1);
    Pack16 p;
    p.h[0] = hx; p.h[1] = hy; p.h[2] = hz; p.h[3] = h1; p.h[4] = h2;
    p.h[5] = (_Float16)0.0f; p.h[6] = (_Float16)0.0f; p.h[7] = (_Float16)0.0f;
    (arr ? packT : packP)[pt] = p.f4;
}

__device__ inline half8 make_bfrag(const Pack16& praw, bool lo) {
    half8 f;
#pragma unroll
    for (int i = 0; i < 8; ++i) f[i] = (_Float16)0.0f;
    if (lo) {
        f[0] = (_Float16)(praw.h[0] * (_Float16)-2.0f);  // exact x2 scale
        f[1] = (_Float16)(praw.h[1] * (_Float16)-2.0f);
        f[2] = (_Float16)(praw.h[2] * (_Float16)-2.0f);
        f[3] = (_Float16)1.0f;
        f[4] = (_Float16)1.0f;
    }
    return f;
}

__global__ __launch_bounds__(THREADS, 2) void chamfer_main(
    const float4* __restrict__ packP, const float4* __restrict__ packT,
    float* __restrict__ blocksum)
{
    __shared__ Pack16 bufA[1024];   // chalf0 chunk (16 KB), waves 0-3
    __shared__ Pack16 bufB[1024];   // chalf1 chunk (16 KB), waves 4-7
    __shared__ float pmin[8][64];   // per-wave mins for its 64 queries
    __shared__ float wsum[4];

    int tid  = threadIdx.x;
    int lane = tid & 63;
    int wave = tid >> 6;            // 0..7
    int qhalf = wave & 3;           // query 64-set (0..3) within the block's 256
    int chalf = wave >> 2;          // candidate half (2048 candidates)
    int l31  = lane & 31;
    bool lo  = lane < 32;

    int id = blockIdx.x;
    int ng = id & 15; id >>= 4;     // query group (256 queries)
    int b  = id & 15; id >>= 4;
    int dir = id;                   // 0: queries=pred, candidates=target

    const float4* qpack = dir ? packT : packP;
    const float4* cpack = dir ? packP : packT;

    // Two B fragments per wave: queries [qbase, qbase+32) and [qbase+32, qbase+64).
    size_t qbase = (size_t)b * NPTS + ng * QPB + qhalf * 64;
    Pack16 prA, prB;
    prA.f4 = qpack[qbase + l31];
    prB.f4 = qpack[qbase + 32 + l31];
    half8 bfragA = make_bfrag(prA, lo);
    half8 bfragB = make_bfrag(prB, lo);

    const float4* cb = cpack + (size_t)b * NPTS;   // all 4096 candidates of batch b

    floatx16 zero, mnA, mnB;
#pragma unroll
    for (int r = 0; r < 16; ++r) { zero[r] = 0.0f; mnA[r] = 1e30f; mnB[r] = 1e30f; }

    // 2 phases x 1024 candidates per chalf. Staging: waves 0-3 fill bufA
    // (chalf0 chunk), waves 4-7 fill bufB (chalf1 chunk) — each tile is loaded
    // from L2 ONCE per block and consumed by 4 waves (was: 4 separate global
    // loads). Compute body = R14 verbatim, reading from LDS.
#pragma unroll 1
    for (int k = 0; k < 2; ++k) {
        if (k) __syncthreads();     // all waves done reading bufs of phase k-1
        if (wave < 4) {
            const float4* srcA = cb + k * 1024;            // chalf0 chunk
#pragma unroll
            for (int i = 0; i < 4; ++i)
                GLL(srcA + wave * 256 + i * 64 + lane, &bufA[wave * 256 + i * 64]);
        } else {
            const float4* srcB = cb + 2048 + k * 1024;     // chalf1 chunk
#pragma unroll
            for (int i = 0; i < 4; ++i)
                GLL(srcB + (wave - 4) * 256 + i * 64 + lane, &bufB[(wave - 4) * 256 + i * 64]);
        }
        __syncthreads();            // gll queue drains (vmcnt) before barrier

        const Pack16* buf = (wave < 4) ? bufA : bufB;
#pragma unroll 2
        for (int t = 0; t < 16; ++t) {
            Pack16 a0, a1;
            a0.f4 = buf[t * 64 + l31].f4;
            a1.f4 = buf[t * 64 + 32 + l31].f4;
            floatx16 d0 = __builtin_amdgcn_mfma_f32_32x32x16_f16(a0.h8, bfragA, zero, 0, 0, 0);
            floatx16 d1 = __builtin_amdgcn_mfma_f32_32x32x16_f16(a0.h8, bfragB, zero, 0, 0, 0);
#pragma unroll
            for (int r = 0; r < 16; ++r) mnA[r] = fminf(d0[r], mnA[r]);
#pragma unroll
            for (int r = 0; r < 16; ++r) mnB[r] = fminf(d1[r], mnB[r]);
            floatx16 d2 = __builtin_amdgcn_mfma_f32_32x32x16_f16(a1.h8, bfragA, zero, 0, 0, 0);
            floatx16 d3 = __builtin_amdgcn_mfma_f32_32x32x16_f16(a1.h8, bfragB, zero, 0, 0, 0);
#pragma unroll
            for (int r = 0; r < 16; ++r) mnA[r] = fminf(d2[r], mnA[r]);
#pragma unroll
            for (int r = 0; r < 16; ++r) mnB[r] = fminf(d3[r], mnB[r]);
        }
    }

    // Per-lane 16-reg min trees, fold row-halves across lane^32, publish both
    // query sets (cols l31 / l31+32 of pmin row).
    float mA = fminf(fminf(fminf(mnA[0], mnA[1]),   fminf(mnA[2], mnA[3])),
                     fminf(fminf(mnA[4], mnA[5]),   fminf(mnA[6], mnA[7])));
    mA = fminf(mA, fminf(fminf(fminf(mnA[8], mnA[9]),   fminf(mnA[10], mnA[11])),
                         fminf(fminf(mnA[12], mnA[13]), fminf(mnA[14], mnA[15]))));
    float mB = fminf(fminf(fminf(mnB[0], mnB[1]),   fminf(mnB[2], mnB[3])),
                     fminf(fminf(mnB[4], mnB[5]),   fminf(mnB[6], mnB[7])));
    mB = fminf(mB, fminf(fminf(fminf(mnB[8], mnB[9]),   fminf(mnB[10], mnB[11])),
                         fminf(fminf(mnB[12], mnB[13]), fminf(mnB[14], mnB[15]))));
    mA = fminf(mA, __shfl_xor(mA, 32));
    mB = fminf(mB, __shfl_xor(mB, 32));
    if (lo) {
        pmin[wave][l31]      = mA;
        pmin[wave][l31 + 32] = mB;
    }
    __syncthreads();

    // Waves 0-3: all 64 lanes finish one query each (query = ng*256 + wave*64 + lane):
    // merge candidate halves (wave w vs w+4), add |p|^2, sqrt, full-wave sum.
    if (wave < 4) {
        float mm = fminf(pmin[wave][lane], pmin[wave + 4][lane]);
        Pack16 pr;
        pr.f4 = qpack[(size_t)b * NPTS + ng * QPB + wave * 64 + lane];
        float psq = (float)pr.h[3] + (float)pr.h[4];
        float dist = sqrtf(fmaxf(mm + psq, 0.0f));
#pragma unroll
        for (int off = 1; off <= 32; off <<= 1)
            dist += __shfl_xor(dist, off);
        if (lane == 0) wsum[wave] = dist;
    }
    __syncthreads();

    if (tid == 0)
        blocksum[blockIdx.x] = (wsum[0] + wsum[1]) + (wsum[2] + wsum[3]);
}

__global__ __launch_bounds__(256) void chamfer_finish(
    const float4* __restrict__ bs, float* __restrict__ out)
{
    __shared__ float ws[4];
    int tid = threadIdx.x;
    float s = 0.0f;
    if (tid < 128) {                      // 512 block sums = 128 x float4
        float4 v = bs[tid];
        s = (v.x + v.y) + (v.z + v.w);
    }
#pragma unroll
    for (int off = 1; off <= 32; off <<= 1)
        s += __shfl_xor(s, off);
    int lane = tid & 63, wave = tid >> 6;
    if (lane == 0) ws[wave] = s;
    __syncthreads();
    if (tid == 0) out[0] = (ws[0] + ws[1] + ws[2] + ws[3]) * (1.0f / (float)NITEMS);
}

extern "C" void kernel_launch(void* const* d_in, const int* in_sizes, int n_in,
                              void* d_out, int out_size, void* d_ws, size_t ws_size,
                              hipStream_t stream) {
    const float* pred   = (const float*)d_in[0];
    const float* target = (const float*)d_in[1];
    float* out = (float*)d_out;

    float4* packP = (float4*)d_ws;                              // 1 MB
    float4* packT = packP + (size_t)BATCH * NPTS;               // 1 MB
    float*  blocksum = (float*)(packT + (size_t)BATCH * NPTS);  // 2 KB

    chamfer_prep<<<NITEMS / 256, 256, 0, stream>>>(pred, target, packP, packT);
    chamfer_main<<<MAIN_BLOCKS, THREADS, 0, stream>>>(packP, packT, blocksum);
    chamfer_finish<<<1, 256, 0, stream>>>((const float4*)blocksum, out);
}